// Round 5
// baseline (886.340 us; speedup 1.0000x reference)
//
#include <hip/hip_runtime.h>

// LJ 12-6 over a neighbor list — round 5: tile-bucketed pairs, LDS gathers.
// R2-R4 established a hard ~3.4 cyc per divergent lane-gather per CU wall
// (time invariant to occupancy 27-44% and batching 8-16). Fix: bucket pairs
// by (i_block, j_block) tiles of 4096 atoms, stage both blocks in LDS, turn
// all 25.6M random global gathers into LDS reads.

typedef int   v4i __attribute__((ext_vector_type(4)));
typedef float v4f __attribute__((ext_vector_type(4)));

#define BLK_SHIFT 12
#define BLK       4096        // atoms per block (49 blocks @ N=200k, 2401 tiles)
#define MAXNT     2432        // LDS histogram capacity (>= nt)
#define CHUNK     24576       // pairs per workgroup in scatter pass
#define OVF_CAP   (1u << 20)  // overflow pair capacity (astronomically rare)

__device__ __forceinline__ void lj_accum(
    float dx, float dy, float dz, float eps, float s2, float cut2,
    int gi, float* __restrict__ energy, float* __restrict__ forces)
{
    const float r2 = dx * dx + dy * dy + dz * dz;
    if (r2 < cut2 && r2 > 1e-10f) {
        const float inv  = 1.0f / r2;
        const float sr2  = s2 * inv;
        const float sr6  = sr2 * sr2 * sr2;
        const float sr12 = sr6 * sr6;
        const float e    = 2.0f * eps * (sr12 - sr6);              // 0.5 * 4eps
        const float f    = 24.0f * eps * (2.0f * sr12 - sr6) * inv;
        atomicAdd(&energy[gi], e);
        atomicAdd(&forces[3 * gi + 0], f * dx);
        atomicAdd(&forces[3 * gi + 1], f * dy);
        atomicAdd(&forces[3 * gi + 2], f * dz);
    }
}

__global__ void __launch_bounds__(256) pad_R_kernel(
    const float* __restrict__ R, v4f* __restrict__ Rp, int n_atoms)
{
    int a = blockIdx.x * blockDim.x + threadIdx.x;
    if (a < n_atoms) {
        v4f v;
        v.x = R[3 * a + 0];
        v.y = R[3 * a + 1];
        v.z = R[3 * a + 2];
        v.w = 0.0f;
        Rp[a] = v;
    }
}

// Pass A: counting-scatter pairs into per-tile lists.
__global__ void __launch_bounds__(256) scatter_kernel(
    const int* __restrict__ idx_i, const int* __restrict__ idx_j,
    unsigned* __restrict__ cursor,     // [nt] zeroed
    unsigned* __restrict__ pair_buf,   // [nt * cap]
    int2* __restrict__ ovf_buf, unsigned* __restrict__ ovf_cnt,
    int n_pairs, int nb, int nt, int cap)
{
    __shared__ unsigned hist[MAXNT];
    __shared__ unsigned base[MAXNT];

    const int p0   = blockIdx.x * CHUNK;
    const int pend = min(p0 + CHUNK, n_pairs);

    for (int t = threadIdx.x; t < nt; t += 256) hist[t] = 0;
    __syncthreads();

    // sweep 1: local histogram
    for (int p = p0 + threadIdx.x; p < pend; p += 256) {
        int i = idx_i[p], j = idx_j[p];
        int t = (i >> BLK_SHIFT) * nb + (j >> BLK_SHIFT);
        atomicAdd(&hist[t], 1u);
    }
    __syncthreads();

    // reserve contiguous ranges in each tile's region
    for (int t = threadIdx.x; t < nt; t += 256) {
        unsigned c = hist[t];
        base[t] = c ? atomicAdd(&cursor[t], c) : 0u;
        hist[t] = 0;
    }
    __syncthreads();

    // sweep 2: re-read chunk, scatter packed locals
    for (int p = p0 + threadIdx.x; p < pend; p += 256) {
        int i = idx_i[p], j = idx_j[p];
        int t = (i >> BLK_SHIFT) * nb + (j >> BLK_SHIFT);
        unsigned r = base[t] + atomicAdd(&hist[t], 1u);
        if (r < (unsigned)cap) {
            unsigned pk = ((unsigned)(i & (BLK - 1)) << BLK_SHIFT) | (unsigned)(j & (BLK - 1));
            __builtin_nontemporal_store(pk, &pair_buf[(size_t)t * cap + r]);
        } else {
            unsigned o = atomicAdd(ovf_cnt, 1u);
            if (o < OVF_CAP) ovf_buf[o] = make_int2(i, j);
        }
    }
}

// Pass B: one workgroup per tile; both atom blocks staged in LDS.
__global__ void __launch_bounds__(256) tile_kernel(
    const v4f* __restrict__ Rp,
    const unsigned* __restrict__ cursor,
    const unsigned* __restrict__ pair_buf,
    const float* __restrict__ eps_p,
    const float* __restrict__ sig_p,
    const float* __restrict__ cut_p,
    float* __restrict__ energy,
    float* __restrict__ forces,
    int n_atoms, int nb, int cap)
{
    extern __shared__ v4f smem[];          // [2*BLK] = 128 KB dynamic LDS
    v4f* sI = smem;
    v4f* sJ = smem + BLK;

    const int t  = blockIdx.x;
    const int ib = t / nb;
    const int jb = t - ib * nb;

    const v4f zero = {0.0f, 0.0f, 0.0f, 0.0f};
    for (int k = threadIdx.x; k < BLK; k += 256) {
        int a = ib * BLK + k;
        sI[k] = (a < n_atoms) ? Rp[a] : zero;
        int b = jb * BLK + k;
        sJ[k] = (b < n_atoms) ? Rp[b] : zero;
    }
    __syncthreads();

    const float eps  = eps_p[0];
    const float sig  = sig_p[0];
    const float cut  = cut_p[0];
    const float s2   = sig * sig;
    const float cut2 = cut * cut;

    unsigned c = cursor[t];
    if (c > (unsigned)cap) c = (unsigned)cap;

    const unsigned* tp = pair_buf + (size_t)t * cap;
    for (unsigned r = threadIdx.x; r < c; r += 256) {
        unsigned pk = __builtin_nontemporal_load(&tp[r]);
        int il = pk >> BLK_SHIFT;
        int jl = pk & (BLK - 1);
        v4f A = sI[il];
        v4f B = sJ[jl];
        lj_accum(A.x - B.x, A.y - B.y, A.z - B.z, eps, s2, cut2,
                 ib * BLK + il, energy, forces);
    }
}

// Overflow pairs (rare): direct random-gather path.
__global__ void __launch_bounds__(256) ovf_kernel(
    const v4f* __restrict__ Rp,
    const int2* __restrict__ ovf_buf, const unsigned* __restrict__ ovf_cnt,
    const float* __restrict__ eps_p,
    const float* __restrict__ sig_p,
    const float* __restrict__ cut_p,
    float* __restrict__ energy, float* __restrict__ forces)
{
    unsigned n = *ovf_cnt;
    if (n > OVF_CAP) n = OVF_CAP;
    const float eps  = eps_p[0];
    const float sig  = sig_p[0];
    const float cut  = cut_p[0];
    const float s2   = sig * sig;
    const float cut2 = cut * cut;
    for (unsigned p = blockIdx.x * blockDim.x + threadIdx.x; p < n;
         p += gridDim.x * blockDim.x) {
        int2 ij = ovf_buf[p];
        v4f A = Rp[ij.x];
        v4f B = Rp[ij.y];
        lj_accum(A.x - B.x, A.y - B.y, A.z - B.z, eps, s2, cut2,
                 ij.x, energy, forces);
    }
}

// ---------- fallback path (R2 structure, 131 us) if ws is too small ----------
#define PPT 8
__global__ void __launch_bounds__(256) lj_pairs_fb_kernel(
    const v4f* __restrict__ Rp,
    const v4i* __restrict__ idx_i4, const v4i* __restrict__ idx_j4,
    const float* __restrict__ eps_p, const float* __restrict__ sig_p,
    const float* __restrict__ cut_p,
    float* __restrict__ energy, float* __restrict__ forces, int n_oct)
{
    int t = blockIdx.x * blockDim.x + threadIdx.x;
    if (t >= n_oct) return;
    const float eps  = eps_p[0];
    const float sig  = sig_p[0];
    const float cut  = cut_p[0];
    const float s2   = sig * sig;
    const float cut2 = cut * cut;
    v4i ii0 = __builtin_nontemporal_load(idx_i4 + 2 * t);
    v4i ii1 = __builtin_nontemporal_load(idx_i4 + 2 * t + 1);
    v4i jj0 = __builtin_nontemporal_load(idx_j4 + 2 * t);
    v4i jj1 = __builtin_nontemporal_load(idx_j4 + 2 * t + 1);
    int is[PPT] = { ii0.x, ii0.y, ii0.z, ii0.w, ii1.x, ii1.y, ii1.z, ii1.w };
    int js[PPT] = { jj0.x, jj0.y, jj0.z, jj0.w, jj1.x, jj1.y, jj1.z, jj1.w };
    v4f Ri[PPT], Rj[PPT];
#pragma unroll
    for (int k = 0; k < PPT; ++k) Ri[k] = Rp[is[k]];
#pragma unroll
    for (int k = 0; k < PPT; ++k) Rj[k] = Rp[js[k]];
#pragma unroll
    for (int k = 0; k < PPT; ++k)
        lj_accum(Ri[k].x - Rj[k].x, Ri[k].y - Rj[k].y, Ri[k].z - Rj[k].z,
                 eps, s2, cut2, is[k], energy, forces);
}

__global__ void lj_pairs_fb_tail_kernel(
    const v4f* __restrict__ Rp,
    const int* __restrict__ idx_i, const int* __restrict__ idx_j,
    const float* __restrict__ eps_p, const float* __restrict__ sig_p,
    const float* __restrict__ cut_p,
    float* __restrict__ energy, float* __restrict__ forces,
    int start, int n_pairs)
{
    int p = start + blockIdx.x * blockDim.x + threadIdx.x;
    if (p >= n_pairs) return;
    const float eps  = eps_p[0];
    const float sig  = sig_p[0];
    const float cut  = cut_p[0];
    v4f A = Rp[idx_i[p]];
    v4f B = Rp[idx_j[p]];
    lj_accum(A.x - B.x, A.y - B.y, A.z - B.z, eps, sig * sig, cut * cut,
             idx_i[p], energy, forces);
}
// -----------------------------------------------------------------------------

extern "C" void kernel_launch(void* const* d_in, const int* in_sizes, int n_in,
                              void* d_out, int out_size, void* d_ws, size_t ws_size,
                              hipStream_t stream) {
    const float* R     = (const float*)d_in[0];
    const float* eps_p = (const float*)d_in[1];
    const float* sig_p = (const float*)d_in[2];
    const float* cut_p = (const float*)d_in[3];
    const int*   idx_i = (const int*)d_in[4];
    const int*   idx_j = (const int*)d_in[5];

    const int n_atoms = in_sizes[0] / 3;
    const int n_pairs = in_sizes[4];
    const int nb = (n_atoms + BLK - 1) >> BLK_SHIFT;
    const int nt = nb * nb;

    float* energy = (float*)d_out;
    float* forces = (float*)d_out + n_atoms;

    hipMemsetAsync(d_out, 0, (size_t)out_size * sizeof(float), stream);

    // ws layout: [Rp][cursor + ovf_cnt][pair_buf][ovf_buf]
    char* ws = (char*)d_ws;
    const size_t rp_b   = (((size_t)n_atoms * 16) + 255) & ~(size_t)255;
    const size_t meta_b = (((size_t)nt * 4 + 16) + 255) & ~(size_t)255;
    const size_t ovf_b  = (size_t)OVF_CAP * 8;

    long long cap = 0;
    if (nt <= MAXNT && ws_size > rp_b + meta_b + ovf_b) {
        cap = (long long)((ws_size - rp_b - meta_b - ovf_b) / ((size_t)nt * 4));
        if (cap > 8192) cap = 8192;
    }
    const bool use_sorted = (cap >= 5632) && (ws_size >= rp_b);
    const bool have_rp    = ws_size >= rp_b;

    v4f*      Rp       = (v4f*)ws;
    unsigned* cursor   = (unsigned*)(ws + rp_b);
    unsigned* ovf_cnt  = cursor + nt;
    unsigned* pair_buf = (unsigned*)(ws + rp_b + meta_b);
    int2*     ovf_buf  = (int2*)(ws + rp_b + meta_b + (size_t)nt * (size_t)cap * 4);

    if (have_rp) {
        int blocks = (n_atoms + 255) / 256;
        pad_R_kernel<<<blocks, 256, 0, stream>>>(R, Rp, n_atoms);
    }

    if (use_sorted) {
        hipMemsetAsync(cursor, 0, (size_t)nt * 4 + 16, stream);

        int a_blocks = (n_pairs + CHUNK - 1) / CHUNK;
        scatter_kernel<<<a_blocks, 256, 0, stream>>>(
            idx_i, idx_j, cursor, pair_buf, ovf_buf, ovf_cnt,
            n_pairs, nb, nt, (int)cap);

        static bool attr_done = false;
        if (!attr_done) {
            hipFuncSetAttribute((const void*)tile_kernel,
                                hipFuncAttributeMaxDynamicSharedMemorySize,
                                2 * BLK * 16);
            attr_done = true;
        }
        tile_kernel<<<nt, 256, 2 * BLK * 16, stream>>>(
            Rp, cursor, pair_buf, eps_p, sig_p, cut_p,
            energy, forces, n_atoms, nb, (int)cap);

        ovf_kernel<<<128, 256, 0, stream>>>(
            Rp, ovf_buf, ovf_cnt, eps_p, sig_p, cut_p, energy, forces);
    } else {
        // fallback: R2 random-gather path (requires only Rp in ws; if even
        // that is missing, ws is unusable — Rp path verified in round 1)
        const int n_oct = n_pairs / PPT;
        const int start = n_oct * PPT;
        if (n_oct > 0) {
            int blocks = (n_oct + 255) / 256;
            lj_pairs_fb_kernel<<<blocks, 256, 0, stream>>>(
                Rp, (const v4i*)idx_i, (const v4i*)idx_j,
                eps_p, sig_p, cut_p, energy, forces, n_oct);
        }
        if (start < n_pairs) {
            lj_pairs_fb_tail_kernel<<<1, 64, 0, stream>>>(
                Rp, idx_i, idx_j, eps_p, sig_p, cut_p,
                energy, forces, start, n_pairs);
        }
    }
}

// Round 6
// 210.185 us; speedup vs baseline: 4.2169x; 4.2169x over previous
//
#include <hip/hip_runtime.h>

// LJ 12-6 over a neighbor list — round 6: LDS-resident cell filter.
// R2-R4: direct path pinned at ~3.3 cyc per divergent lane-gather per CU
// (131 us for 25.6M requests). R5: global scatter-sort catastrophically
// write-amplified (4B random stores -> 404MB HBM RMW, 605 us).
// This round: 4x4x4 cell grid (15A >= cutoff 10A), 6-bit cell ids packed
// into 150KB LDS. Conservative filter (per-dim cell diff <= 1) keeps 24.4%
// of random pairs (incl. ALL true pairs) -> gather requests 25.6M -> 6.25M.

typedef int   v4i __attribute__((ext_vector_type(4)));
typedef float v4f __attribute__((ext_vector_type(4)));

#define CELL_SZ   15.0f
#define INV_CELL  (1.0f / 15.0f)
#define GRP       8
#define WGT       1024     // 1 WG/CU (LDS-bound) -> still 16 waves/CU
#define NWG       1024

__global__ void __launch_bounds__(256) pad_R_kernel(
    const float* __restrict__ R, v4f* __restrict__ Rp, int n_atoms)
{
    int a = blockIdx.x * blockDim.x + threadIdx.x;
    if (a < n_atoms) {
        v4f v;
        v.x = R[3 * a + 0];
        v.y = R[3 * a + 1];
        v.z = R[3 * a + 2];
        v.w = 0.0f;
        Rp[a] = v;  // 16B aligned: single-transaction gathers
    }
}

// Pack 6-bit cell ids: thread t owns atoms [16t,16t+16) -> 96 bits -> 3 words
// (exclusive word ranges, no write races).
__global__ void __launch_bounds__(256) cell_kernel(
    const float* __restrict__ R, unsigned* __restrict__ packed, int n_atoms)
{
    int t = blockIdx.x * blockDim.x + threadIdx.x;
    int n_thr = (n_atoms + 15) >> 4;
    if (t >= n_thr) return;
    int a0 = t << 4;
    unsigned w[3] = {0u, 0u, 0u};
#pragma unroll
    for (int k = 0; k < 16; ++k) {
        int a = a0 + k;
        unsigned c = 0u;
        if (a < n_atoms) {
            int cx = min(3, max(0, (int)(R[3 * a + 0] * INV_CELL)));
            int cy = min(3, max(0, (int)(R[3 * a + 1] * INV_CELL)));
            int cz = min(3, max(0, (int)(R[3 * a + 2] * INV_CELL)));
            c = (unsigned)(cx | (cy << 2) | (cz << 4));
        }
        int bit = 6 * k, word = bit >> 5, off = bit & 31;
        w[word] |= c << off;
        if (off > 26) w[word + 1] |= c >> (32 - off);
    }
    packed[3 * t + 0] = w[0];
    packed[3 * t + 1] = w[1];
    packed[3 * t + 2] = w[2];
}

__device__ __forceinline__ unsigned cell6(const unsigned char* c8, unsigned a) {
    unsigned bit = a * 6u;
    unsigned by  = bit >> 3;
    unsigned v   = (unsigned)c8[by] | ((unsigned)c8[by + 1] << 8);
    return (v >> (bit & 7u)) & 63u;
}

__global__ void __launch_bounds__(WGT) lj_filter_kernel(
    const v4f* __restrict__ Rp,
    const unsigned* __restrict__ packed,   // pk_words words (incl. +1 pad)
    const int* __restrict__ idx_i,
    const int* __restrict__ idx_j,
    const float* __restrict__ eps_p,
    const float* __restrict__ sig_p,
    const float* __restrict__ cut_p,
    float* __restrict__ energy,            // [N]
    float* __restrict__ forces,            // [N,3]
    int n_pairs, int pk_words, int chunk)
{
    extern __shared__ unsigned lds[];
    for (int w = threadIdx.x; w < pk_words; w += WGT)
        lds[w] = packed[w];
    __syncthreads();
    const unsigned char* c8 = (const unsigned char*)lds;

    const float eps  = eps_p[0];
    const float sig  = sig_p[0];
    const float cut  = cut_p[0];
    const float s2   = sig * sig;
    const float cut2 = cut * cut;
    // filter valid only while cell size >= cutoff; else pass everything
    const bool nofilter = (cut2 > CELL_SZ * CELL_SZ);

    const int cs = blockIdx.x * chunk;
    const int ce = min(cs + chunk, n_pairs);

    for (int p = cs + threadIdx.x * GRP; p < ce; p += WGT * GRP) {
        int is8[GRP], js8[GRP];
        if (p + GRP <= n_pairs) {   // p % 8 == 0 -> int4-aligned
            v4i a0 = __builtin_nontemporal_load((const v4i*)idx_i + (p >> 2));
            v4i a1 = __builtin_nontemporal_load((const v4i*)idx_i + (p >> 2) + 1);
            v4i b0 = __builtin_nontemporal_load((const v4i*)idx_j + (p >> 2));
            v4i b1 = __builtin_nontemporal_load((const v4i*)idx_j + (p >> 2) + 1);
            is8[0] = a0.x; is8[1] = a0.y; is8[2] = a0.z; is8[3] = a0.w;
            is8[4] = a1.x; is8[5] = a1.y; is8[6] = a1.z; is8[7] = a1.w;
            js8[0] = b0.x; js8[1] = b0.y; js8[2] = b0.z; js8[3] = b0.w;
            js8[4] = b1.x; js8[5] = b1.y; js8[6] = b1.z; js8[7] = b1.w;
        } else {
            for (int k = 0; k < GRP; ++k) {
                is8[k] = (p + k < n_pairs) ? idx_i[p + k] : 0;
                js8[k] = (p + k < n_pairs) ? idx_j[p + k] : 0;
                // padded entries: i==j==0 -> r2==0 -> rejected by r2>1e-10
            }
        }

        // Phase 1: LDS cell filter (24.4% pass for random pairs)
        unsigned m = 0u;
#pragma unroll
        for (int k = 0; k < GRP; ++k) {
            unsigned ci = cell6(c8, (unsigned)is8[k]);
            unsigned cj = cell6(c8, (unsigned)js8[k]);
            int ddx = (int)(ci & 3u)        - (int)(cj & 3u);
            int ddy = (int)((ci >> 2) & 3u) - (int)((cj >> 2) & 3u);
            int ddz = (int)(ci >> 4)        - (int)(cj >> 4);
            bool ok = ((unsigned)(ddx + 1) <= 2u) & ((unsigned)(ddy + 1) <= 2u)
                    & ((unsigned)(ddz + 1) <= 2u);
            if (ok | nofilter) m |= (1u << k);
        }

        // Phase 2: exec-masked gathers — masked lanes issue NO requests
        v4f Ri[GRP], Rj[GRP];
#pragma unroll
        for (int k = 0; k < GRP; ++k)
            if (m & (1u << k)) { Ri[k] = Rp[is8[k]]; Rj[k] = Rp[js8[k]]; }

        // Phase 3: compute + sparse atomics (1.9% true pairs)
#pragma unroll
        for (int k = 0; k < GRP; ++k) {
            if (m & (1u << k)) {
                const float dx = Ri[k].x - Rj[k].x;
                const float dy = Ri[k].y - Rj[k].y;
                const float dz = Ri[k].z - Rj[k].z;
                const float r2 = dx * dx + dy * dy + dz * dz;
                if (r2 < cut2 && r2 > 1e-10f) {
                    const float inv  = 1.0f / r2;
                    const float sr2  = s2 * inv;
                    const float sr6  = sr2 * sr2 * sr2;
                    const float sr12 = sr6 * sr6;
                    const float e    = 2.0f * eps * (sr12 - sr6);   // 0.5*4eps
                    const float f    = 24.0f * eps * (2.0f * sr12 - sr6) * inv;
                    const int i = is8[k];
                    atomicAdd(&energy[i], e);
                    atomicAdd(&forces[3 * i + 0], f * dx);
                    atomicAdd(&forces[3 * i + 1], f * dy);
                    atomicAdd(&forces[3 * i + 2], f * dz);
                }
            }
        }
    }
}

// ---------- fallback (R2 structure) if ws/LDS insufficient ----------
#define PPT 8
__global__ void __launch_bounds__(256) lj_pairs_fb_kernel(
    const v4f* __restrict__ Rp,
    const v4i* __restrict__ idx_i4, const v4i* __restrict__ idx_j4,
    const float* __restrict__ eps_p, const float* __restrict__ sig_p,
    const float* __restrict__ cut_p,
    float* __restrict__ energy, float* __restrict__ forces, int n_oct)
{
    int t = blockIdx.x * blockDim.x + threadIdx.x;
    if (t >= n_oct) return;
    const float eps  = eps_p[0];
    const float sig  = sig_p[0];
    const float cut  = cut_p[0];
    const float s2   = sig * sig;
    const float cut2 = cut * cut;
    v4i ii0 = __builtin_nontemporal_load(idx_i4 + 2 * t);
    v4i ii1 = __builtin_nontemporal_load(idx_i4 + 2 * t + 1);
    v4i jj0 = __builtin_nontemporal_load(idx_j4 + 2 * t);
    v4i jj1 = __builtin_nontemporal_load(idx_j4 + 2 * t + 1);
    int is[PPT] = { ii0.x, ii0.y, ii0.z, ii0.w, ii1.x, ii1.y, ii1.z, ii1.w };
    int js[PPT] = { jj0.x, jj0.y, jj0.z, jj0.w, jj1.x, jj1.y, jj1.z, jj1.w };
    v4f Ri[PPT], Rj[PPT];
#pragma unroll
    for (int k = 0; k < PPT; ++k) Ri[k] = Rp[is[k]];
#pragma unroll
    for (int k = 0; k < PPT; ++k) Rj[k] = Rp[js[k]];
#pragma unroll
    for (int k = 0; k < PPT; ++k) {
        const float dx = Ri[k].x - Rj[k].x;
        const float dy = Ri[k].y - Rj[k].y;
        const float dz = Ri[k].z - Rj[k].z;
        const float r2 = dx * dx + dy * dy + dz * dz;
        if (r2 < cut2 && r2 > 1e-10f) {
            const float inv  = 1.0f / r2;
            const float sr2  = s2 * inv;
            const float sr6  = sr2 * sr2 * sr2;
            const float sr12 = sr6 * sr6;
            const float e    = 2.0f * eps * (sr12 - sr6);
            const float f    = 24.0f * eps * (2.0f * sr12 - sr6) * inv;
            const int i = is[k];
            atomicAdd(&energy[i], e);
            atomicAdd(&forces[3 * i + 0], f * dx);
            atomicAdd(&forces[3 * i + 1], f * dy);
            atomicAdd(&forces[3 * i + 2], f * dz);
        }
    }
}

__global__ void lj_pairs_fb_tail_kernel(
    const v4f* __restrict__ Rp,
    const int* __restrict__ idx_i, const int* __restrict__ idx_j,
    const float* __restrict__ eps_p, const float* __restrict__ sig_p,
    const float* __restrict__ cut_p,
    float* __restrict__ energy, float* __restrict__ forces,
    int start, int n_pairs)
{
    int p = start + blockIdx.x * blockDim.x + threadIdx.x;
    if (p >= n_pairs) return;
    const float eps  = eps_p[0];
    const float sig  = sig_p[0];
    const float cut  = cut_p[0];
    const float s2   = sig * sig;
    const float cut2 = cut * cut;
    const int i = idx_i[p];
    v4f A = Rp[i];
    v4f B = Rp[idx_j[p]];
    const float dx = A.x - B.x, dy = A.y - B.y, dz = A.z - B.z;
    const float r2 = dx * dx + dy * dy + dz * dz;
    if (r2 < cut2 && r2 > 1e-10f) {
        const float inv  = 1.0f / r2;
        const float sr2  = s2 * inv;
        const float sr6  = sr2 * sr2 * sr2;
        const float sr12 = sr6 * sr6;
        const float e    = 2.0f * eps * (sr12 - sr6);
        const float f    = 24.0f * eps * (2.0f * sr12 - sr6) * inv;
        atomicAdd(&energy[i], e);
        atomicAdd(&forces[3 * i + 0], f * dx);
        atomicAdd(&forces[3 * i + 1], f * dy);
        atomicAdd(&forces[3 * i + 2], f * dz);
    }
}
// --------------------------------------------------------------------

extern "C" void kernel_launch(void* const* d_in, const int* in_sizes, int n_in,
                              void* d_out, int out_size, void* d_ws, size_t ws_size,
                              hipStream_t stream) {
    const float* R     = (const float*)d_in[0];
    const float* eps_p = (const float*)d_in[1];
    const float* sig_p = (const float*)d_in[2];
    const float* cut_p = (const float*)d_in[3];
    const int*   idx_i = (const int*)d_in[4];
    const int*   idx_j = (const int*)d_in[5];

    const int n_atoms = in_sizes[0] / 3;
    const int n_pairs = in_sizes[4];

    float* energy = (float*)d_out;
    float* forces = (float*)d_out + n_atoms;

    // d_out re-poisoned 0xAA before every timed call — zero it.
    hipMemsetAsync(d_out, 0, (size_t)out_size * sizeof(float), stream);

    // ws layout: [Rp float4][packed 6-bit cell table]
    char* ws = (char*)d_ws;
    const size_t rp_b     = (((size_t)n_atoms * 16) + 255) & ~(size_t)255;
    const int    n_thr    = (n_atoms + 15) >> 4;          // packing threads
    const int    pk_store = 3 * n_thr;                    // words written
    const int    pk_words = pk_store + 1;                 // +1 word read pad
    const size_t pk_b     = (((size_t)pk_words * 4) + 255) & ~(size_t)255;
    const size_t lds_b    = (((size_t)pk_words * 4) + 15) & ~(size_t)15;

    const bool have_rp    = ws_size >= rp_b;
    const bool use_filter = have_rp && (ws_size >= rp_b + pk_b)
                            && (lds_b <= 160000);

    v4f*      Rp     = (v4f*)ws;
    unsigned* packed = (unsigned*)(ws + rp_b);

    if (have_rp) {
        int blocks = (n_atoms + 255) / 256;
        pad_R_kernel<<<blocks, 256, 0, stream>>>(R, Rp, n_atoms);
    }

    if (use_filter) {
        int cblocks = (n_thr + 255) / 256;
        cell_kernel<<<cblocks, 256, 0, stream>>>(R, packed, n_atoms);

        // opt in to >64KB dynamic LDS (host-side, idempotent, every call)
        hipFuncSetAttribute((const void*)lj_filter_kernel,
                            hipFuncAttributeMaxDynamicSharedMemorySize,
                            (int)lds_b);

        int chunk = (((n_pairs + NWG - 1) / NWG) + GRP - 1) & ~(GRP - 1);
        lj_filter_kernel<<<NWG, WGT, lds_b, stream>>>(
            Rp, packed, idx_i, idx_j, eps_p, sig_p, cut_p,
            energy, forces, n_pairs, pk_words, chunk);
    } else {
        const int n_oct = n_pairs / PPT;
        const int start = n_oct * PPT;
        if (n_oct > 0) {
            int blocks = (n_oct + 255) / 256;
            lj_pairs_fb_kernel<<<blocks, 256, 0, stream>>>(
                Rp, (const v4i*)idx_i, (const v4i*)idx_j,
                eps_p, sig_p, cut_p, energy, forces, n_oct);
        }
        if (start < n_pairs) {
            lj_pairs_fb_tail_kernel<<<1, 64, 0, stream>>>(
                Rp, idx_i, idx_j, eps_p, sig_p, cut_p,
                energy, forces, start, n_pairs);
        }
    }
}